// Round 1
// 858.407 us; speedup vs baseline: 1.0599x; 1.0599x over previous
//
#include <hip/hip_runtime.h>

#define EB 4          // edges per block
#define NT 384        // threads per block (6 waves)
#define W3S 36        // padded LDS stride (rows stay 16B-aligned; +4 rotates banks per row)

struct F3 { float x, y, z; };   // 12-byte packed store (align 4)

__global__ __launch_bounds__(NT) void singleconv_fused(
    const float* __restrict__ f,
    const float* __restrict__ basis,
    const float* __restrict__ w1,
    const float* __restrict__ b1,
    const float* __restrict__ g1,
    const float* __restrict__ be1,
    const float* __restrict__ w2,
    const float* __restrict__ b2,
    const float* __restrict__ g2,
    const float* __restrict__ be2,
    const float* __restrict__ w3,
    const float* __restrict__ b3,
    float* __restrict__ out)
{
    __shared__ float sf[EB][17];
    __shared__ float sbas[EB][27];
    __shared__ float sh1[EB][32];
    __shared__ alignas(16) float sh2[EB][32];
    __shared__ alignas(16) float sw3[2][96 * W3S];   // double-buffered w3 chunk
    __shared__ float sr[EB * 96];

    const int t  = threadIdx.x;
    const int e0 = blockIdx.x * EB;

    const int re   = t / 96;          // edge this thread owns (dot + epilogue)
    const int rcol = t - re * 96;     // 0..95  (= ci*3 + freq)
    const int wrow = t >> 2;          // w3 staging row (0..95)
    const int wk   = (t & 3) * 8;     // w3 staging col offset

    // ---- early prefetch: w3 chunk 0 + b3 (L2/HBM latency hides under phase 1)
    float4 pa, pb;
    {
        const float4* ws = (const float4*)(w3);
        pa = ws[t * 2];
        pb = ws[t * 2 + 1];
    }
    float bnx = b3[rcol];

    // ---- phase 1: stage f, basis
    if (t < EB * 17) { int e = t / 17, i = t - e * 17; sf[e][i] = f[(e0 + e) * 17 + i]; }
    if (t >= 128 && t < 128 + EB * 27) {
        int q = t - 128, e = q / 27, i = q - e * 27;
        sbas[e][i] = basis[(e0 + e) * 27 + i];
    }
    __syncthreads();

    // ---- layer 1 + LN + ReLU (LN via 32-lane shuffle reduce, no extra barriers)
    if (t < EB * 32) {
        int e = t >> 5, j = t & 31;
        float acc = b1[j];
        #pragma unroll
        for (int k = 0; k < 17; k++) acc += sf[e][k] * w1[j * 17 + k];
        float s = acc;
        #pragma unroll
        for (int m = 16; m >= 1; m >>= 1) s += __shfl_xor(s, m);
        float mu = s * (1.f / 32.f);
        float d  = acc - mu;
        float v  = d * d;
        #pragma unroll
        for (int m = 16; m >= 1; m >>= 1) v += __shfl_xor(v, m);
        float rs = rsqrtf(v * (1.f / 32.f) + 1e-5f);
        sh1[e][j] = fmaxf(d * rs * g1[j] + be1[j], 0.f);
    }
    __syncthreads();

    // ---- layer 2 + LN + ReLU
    if (t < EB * 32) {
        int e = t >> 5, j = t & 31;
        float acc = b2[j];
        #pragma unroll
        for (int k = 0; k < 32; k++) acc += sh1[e][k] * w2[j * 32 + k];
        float s = acc;
        #pragma unroll
        for (int m = 16; m >= 1; m >>= 1) s += __shfl_xor(s, m);
        float mu = s * (1.f / 32.f);
        float d  = acc - mu;
        float v  = d * d;
        #pragma unroll
        for (int m = 16; m >= 1; m >>= 1) v += __shfl_xor(v, m);
        float rs = rsqrtf(v * (1.f / 32.f) + 1e-5f);
        sh2[e][j] = fmaxf(d * rs * g2[j] + be2[j], 0.f);
    }
    __syncthreads();

    // ---- hoist h2 (own edge) into registers: kills 8 ds_read_b128 per co-iter
    float4 hv[8];
    {
        const float4* hp = (const float4*)(&sh2[re][0]);
        #pragma unroll
        for (int k = 0; k < 8; k++) hv[k] = hp[k];
    }

    // ---- epilogue invariants.
    // Output idx = 3*t + s  =>  e = re, dord = rcol>>5, ci = t&31, di = s.
    // The 3 outputs of a thread share one sr triple; basis slice is 9 contiguous
    // loop-invariant floats -> registers (kills 15 ds_read_b32 per co-iter).
    const int dord = rcol >> 5;
    const int ci   = t & 31;
    float br[3][3];   // br[di][f] = B[e, dord, di, f]
    {
        const float* bp = &sbas[re][dord * 9];
        #pragma unroll
        for (int q = 0; q < 9; q++) (&br[0][0])[q] = bp[q];
    }
    const float* rp = &sr[re * 96 + ci * 3];
    float* op = out + (size_t)(e0 + re) * 9216 + dord * 96 + ci * 3;

    // ---- main co loop: double-buffered w3 staging, 2 barriers/iter
    int buf = 0;
    for (int co = 0; co < 32; ++co) {
        // stage current chunk (prefetched regs -> LDS); touches only sw3[buf],
        // whose last readers finished before barrier2 of iter co-2.
        float* wd = &sw3[buf][wrow * W3S + wk];
        *(float4*)(wd)     = pa;
        *(float4*)(wd + 4) = pb;
        float bcur = bnx;

        // prefetch next chunk (consumed next iteration; latency hidden)
        int cn = (co + 1) & 31;   // co=31 redundantly reloads chunk 0 (unused, in-bounds)
        const float4* ws = (const float4*)(w3 + cn * 3072);
        pa  = ws[t * 2];
        pb  = ws[t * 2 + 1];
        bnx = b3[cn * 96 + rcol];

        __syncthreads();   // staging visible; prev epilogue's sr reads done

        // r[e][rcol] = b3 + <w3 row, h2[e]>   (w from LDS, h from regs)
        float acc = bcur;
        const float* wp = &sw3[buf][rcol * W3S];
        #pragma unroll
        for (int k = 0; k < 8; k++) {
            float4 w = *(const float4*)(wp + k * 4);
            acc += w.x * hv[k].x + w.y * hv[k].y + w.z * hv[k].z + w.w * hv[k].w;
        }
        sr[t] = acc;
        __syncthreads();

        // epilogue: 3 consecutive outputs per thread, one 12-B store
        float r0 = rp[0], r1 = rp[1], r2 = rp[2];
        F3 o;
        o.x = r0 * br[0][0] + r1 * br[0][1] + r2 * br[0][2];
        o.y = r0 * br[1][0] + r1 * br[1][1] + r2 * br[1][2];
        o.z = r0 * br[2][0] + r1 * br[2][1] + r2 * br[2][2];
        *(F3*)(op + co * 288) = o;

        buf ^= 1;
    }
}

extern "C" void kernel_launch(void* const* d_in, const int* in_sizes, int n_in,
                              void* d_out, int out_size, void* d_ws, size_t ws_size,
                              hipStream_t stream) {
    const float* f     = (const float*)d_in[0];
    const float* basis = (const float*)d_in[1];
    const float* w1    = (const float*)d_in[2];
    const float* b1    = (const float*)d_in[3];
    const float* g1    = (const float*)d_in[4];
    const float* be1   = (const float*)d_in[5];
    const float* w2    = (const float*)d_in[6];
    const float* b2    = (const float*)d_in[7];
    const float* g2    = (const float*)d_in[8];
    const float* be2   = (const float*)d_in[9];
    const float* w3    = (const float*)d_in[10];
    const float* b3    = (const float*)d_in[11];
    float* out = (float*)d_out;

    dim3 grid(20000 / EB), block(NT);
    hipLaunchKernelGGL(singleconv_fused, grid, block, 0, stream,
                       f, basis, w1, b1, g1, be1, w2, b2, g2, be2, w3, b3, out);
}

// Round 2
// 844.182 us; speedup vs baseline: 1.0777x; 1.0169x over previous
//
#include <hip/hip_runtime.h>

#define EB 16         // edges per block (20000/16 = 1250 blocks exactly)
#define NT 384        // threads per block (6 waves)
#define W3S 36        // padded LDS stride (rows stay 16B-aligned; +4 rotates banks per row)

struct F3 { float x, y, z; };   // 12-byte packed store (align 4)

__global__ __launch_bounds__(NT) void singleconv_fused(
    const float* __restrict__ f,
    const float* __restrict__ basis,
    const float* __restrict__ w1,
    const float* __restrict__ b1,
    const float* __restrict__ g1,
    const float* __restrict__ be1,
    const float* __restrict__ w2,
    const float* __restrict__ b2,
    const float* __restrict__ g2,
    const float* __restrict__ be2,
    const float* __restrict__ w3,
    const float* __restrict__ b3,
    float* __restrict__ out)
{
    __shared__ float sf[EB][17];
    __shared__ float sbas[EB][27];
    __shared__ float sh1[EB][32];
    __shared__ alignas(16) float sh2[EB][32];
    __shared__ alignas(16) float sw3[96 * W3S];   // single buffer (reg prefetch covers latency)
    __shared__ float sr[EB * 96];

    const int t  = threadIdx.x;
    const int e0 = blockIdx.x * EB;

    const int rcol = t % 96;          // w3 row this thread owns (= ci*3 + freq)
    const int eg   = t / 96;          // edge group 0..3
    const int wrow = t >> 2;          // w3 staging row (0..95)
    const int wk   = (t & 3) * 8;     // w3 staging col offset

    // ---- early prefetch: w3 chunk 0 + b3 (latency hides under MLP prologue)
    float4 pa, pb;
    {
        const float4* ws = (const float4*)(w3);
        pa = ws[t * 2];
        pb = ws[t * 2 + 1];
    }
    float bnx = b3[rcol];

    // ---- phase 1: stage f, basis
    if (t < EB * 17) { int e = t / 17, i = t - e * 17; sf[e][i] = f[(e0 + e) * 17 + i]; }
    for (int q = t; q < EB * 27; q += NT) {
        int e = q / 27, i = q - e * 27;
        sbas[e][i] = basis[(e0 + e) * 27 + i];
    }
    __syncthreads();

    // ---- layer 1 + LN + ReLU (512 slots over 384 threads; shuffle-reduce LN)
    for (int slot = t; slot < EB * 32; slot += NT) {
        int e = slot >> 5, j = slot & 31;
        float acc = b1[j];
        #pragma unroll
        for (int k = 0; k < 17; k++) acc += sf[e][k] * w1[j * 17 + k];
        float s = acc;
        #pragma unroll
        for (int m = 16; m >= 1; m >>= 1) s += __shfl_xor(s, m);
        float mu = s * (1.f / 32.f);
        float d  = acc - mu;
        float v  = d * d;
        #pragma unroll
        for (int m = 16; m >= 1; m >>= 1) v += __shfl_xor(v, m);
        float rs = rsqrtf(v * (1.f / 32.f) + 1e-5f);
        sh1[e][j] = fmaxf(d * rs * g1[j] + be1[j], 0.f);
    }
    __syncthreads();

    // ---- layer 2 + LN + ReLU
    for (int slot = t; slot < EB * 32; slot += NT) {
        int e = slot >> 5, j = slot & 31;
        float acc = b2[j];
        #pragma unroll
        for (int k = 0; k < 32; k++) acc += sh1[e][k] * w2[j * 32 + k];
        float s = acc;
        #pragma unroll
        for (int m = 16; m >= 1; m >>= 1) s += __shfl_xor(s, m);
        float mu = s * (1.f / 32.f);
        float d  = acc - mu;
        float v  = d * d;
        #pragma unroll
        for (int m = 16; m >= 1; m >>= 1) v += __shfl_xor(v, m);
        float rs = rsqrtf(v * (1.f / 32.f) + 1e-5f);
        sh2[e][j] = fmaxf(d * rs * g2[j] + be2[j], 0.f);
    }
    __syncthreads();

    // ---- epilogue invariants.
    // Output slot m = t + 384*s  ->  e = eg + 4*s (since 384 = 4*96),
    // dord = rcol>>5, ci = rcol&31 (loop-invariant).  One sr triple feeds
    // the 3 di outputs; basis slice (9 floats) lives in registers.
    const int dord = rcol >> 5;
    const int ci   = rcol & 31;
    float br[4][9];
    const float* rpp[4];
    float* opp[4];
    #pragma unroll
    for (int s = 0; s < 4; s++) {
        int e = eg + 4 * s;
        const float* bp = &sbas[e][dord * 9];
        #pragma unroll
        for (int q = 0; q < 9; q++) br[s][q] = bp[q];
        rpp[s] = &sr[e * 96 + ci * 3];
        opp[s] = out + (size_t)(e0 + e) * 9216 + dord * 96 + ci * 3;
    }

    const int eb  = eg * 4;           // first edge of this thread's dot group
    const int srb = eb * 96 + rcol;   // sr write base

    // ---- main co loop: 1 w3-row read serves 4 edges; 2 barriers/iter
    for (int co = 0; co < 32; ++co) {
        // stage current chunk (prefetched regs -> LDS); prev dot's sw3 reads
        // finished before the prev iteration's second barrier.
        float* wd = &sw3[wrow * W3S + wk];
        *(float4*)(wd)     = pa;
        *(float4*)(wd + 4) = pb;
        float bcur = bnx;

        // prefetch next chunk (co=31 wraps to 0: unused, in-bounds)
        int cn = (co + 1) & 31;
        const float4* ws = (const float4*)(w3 + cn * 3072);
        pa  = ws[t * 2];
        pb  = ws[t * 2 + 1];
        bnx = b3[cn * 96 + rcol];

        __syncthreads();   // staging visible; prev epilogue's sr reads done

        // r[e][rcol] for e = eb..eb+3: w3 row from LDS once, h2 via
        // broadcast reads (<=2 distinct addrs per wave instruction -> free)
        float a0 = bcur, a1 = bcur, a2 = bcur, a3 = bcur;
        const float* wp = &sw3[rcol * W3S];
        #pragma unroll
        for (int k = 0; k < 8; k++) {
            float4 w  = *(const float4*)(wp + k * 4);
            float4 h0 = *(const float4*)(&sh2[eb + 0][k * 4]);
            float4 h1 = *(const float4*)(&sh2[eb + 1][k * 4]);
            float4 h2v= *(const float4*)(&sh2[eb + 2][k * 4]);
            float4 h3 = *(const float4*)(&sh2[eb + 3][k * 4]);
            a0 += w.x * h0.x  + w.y * h0.y  + w.z * h0.z  + w.w * h0.w;
            a1 += w.x * h1.x  + w.y * h1.y  + w.z * h1.z  + w.w * h1.w;
            a2 += w.x * h2v.x + w.y * h2v.y + w.z * h2v.z + w.w * h2v.w;
            a3 += w.x * h3.x  + w.y * h3.y  + w.z * h3.z  + w.w * h3.w;
        }
        sr[srb]       = a0;
        sr[srb + 96]  = a1;
        sr[srb + 192] = a2;
        sr[srb + 288] = a3;

        __syncthreads();   // sr visible; sw3 reads done (safe to restage)

        // epilogue: 12 outputs/thread as 4 x 12-B stores
        const int orow = co * 288;
        #pragma unroll
        for (int s = 0; s < 4; s++) {
            float r0 = rpp[s][0], r1 = rpp[s][1], r2 = rpp[s][2];
            F3 o;
            o.x = r0 * br[s][0] + r1 * br[s][1] + r2 * br[s][2];
            o.y = r0 * br[s][3] + r1 * br[s][4] + r2 * br[s][5];
            o.z = r0 * br[s][6] + r1 * br[s][7] + r2 * br[s][8];
            *(F3*)(opp[s] + orow) = o;
        }
    }
}

extern "C" void kernel_launch(void* const* d_in, const int* in_sizes, int n_in,
                              void* d_out, int out_size, void* d_ws, size_t ws_size,
                              hipStream_t stream) {
    const float* f     = (const float*)d_in[0];
    const float* basis = (const float*)d_in[1];
    const float* w1    = (const float*)d_in[2];
    const float* b1    = (const float*)d_in[3];
    const float* g1    = (const float*)d_in[4];
    const float* be1   = (const float*)d_in[5];
    const float* w2    = (const float*)d_in[6];
    const float* b2    = (const float*)d_in[7];
    const float* g2    = (const float*)d_in[8];
    const float* be2   = (const float*)d_in[9];
    const float* w3    = (const float*)d_in[10];
    const float* b3    = (const float*)d_in[11];
    float* out = (float*)d_out;

    dim3 grid(20000 / EB), block(NT);
    hipLaunchKernelGGL(singleconv_fused, grid, block, 0, stream,
                       f, basis, w1, b1, g1, be1, w2, b2, g2, be2, w3, b3, out);
}